// Round 2
// baseline (3537.016 us; speedup 1.0000x reference)
//
#include <hip/hip_runtime.h>

#define NN 100000

// ---------------- degree / norm ----------------
__global__ __launch_bounds__(256) void degree_kernel(const int* __restrict__ src,
                                                     const int* __restrict__ dst,
                                                     float* deg_out, float* deg_in, int E) {
    int e = blockIdx.x * blockDim.x + threadIdx.x;
    if (e < E) {
        atomicAdd(&deg_out[src[e]], 1.0f);
        atomicAdd(&deg_in[dst[e]], 1.0f);
    }
}

__global__ __launch_bounds__(256) void norm_kernel(float* deg_out, float* deg_in, int N) {
    int i = blockIdx.x * blockDim.x + threadIdx.x;
    if (i < N) {
        deg_out[i] = rsqrtf(fmaxf(deg_out[i], 1.0f));
        deg_in[i]  = rsqrtf(fmaxf(deg_in[i], 1.0f));
    }
}

// ---------------- edge scatter (float4): agg[dst] += h[src] (* norm_out[src]) ----------------
template <int D4, bool SCALE>
__global__ __launch_bounds__(256) void scatter4_kernel(const float4* __restrict__ h,
                                                       const int* __restrict__ src,
                                                       const int* __restrict__ dst,
                                                       const float* __restrict__ no,
                                                       float* __restrict__ agg, int E) {
    int idx = blockIdx.x * 256 + threadIdx.x;
    int total = E * D4;
    if (idx >= total) return;
    int e = idx / D4;
    int f = idx - e * D4;
    int s = src[e];
    int t = dst[e];
    float4 v = h[(size_t)s * D4 + f];
    if (SCALE) {
        float sc = no[s];
        v.x *= sc; v.y *= sc; v.z *= sc; v.w *= sc;
    }
    float* ap = agg + (size_t)t * (4 * D4) + f * 4;
    atomicAdd(ap + 0, v.x);
    atomicAdd(ap + 1, v.y);
    atomicAdd(ap + 2, v.z);
    atomicAdd(ap + 3, v.w);
}

// ---------------- GEMM: out = [relu(] A@W *nin + b [) * nout] ----------------
// Row-scalings commute with @W, so norm_in is applied in the epilogue, and the
// NEXT layer's norm_out gather-scale is pre-applied here too (EPI=true).
// TJ lanes per node (lane-contiguous columns -> conflict-free LDS float4 reads,
// node-groups broadcast). 2 nodes per thread. W chunked BK=64 in LDS.
template <int K, int NOUTP, int TJ, bool EPI>
__global__ __launch_bounds__(256, 4) void gemm_kernel(const float* __restrict__ A,
                                                      const float* __restrict__ W, const int wcols,
                                                      const float* __restrict__ bias,
                                                      const float* __restrict__ nin,
                                                      const float* __restrict__ nout,
                                                      float* __restrict__ out, const int N) {
    constexpr int BK = 64;
    constexpr int ROWS = 256 / TJ;
    constexpr int M2 = 2;
    constexpr int BM = ROWS * M2;           // nodes per block
    constexpr int NJ4 = NOUTP / (TJ * 4);   // float4 column-groups per thread

    __shared__ __align__(16) float Wl[BK * NOUTP];

    const int tid = threadIdx.x;
    const int tj = tid % TJ;
    const int r = tid / TJ;
    const int n0 = blockIdx.x * BM + r * M2;
    const int K4 = K / 4;

    float acc[M2][NJ4 * 4];
#pragma unroll
    for (int m = 0; m < M2; ++m)
#pragma unroll
        for (int j = 0; j < NJ4 * 4; ++j) acc[m][j] = 0.0f;

    const float4* A4 = (const float4*)A;
    const bool v0 = (n0 < N);
    const bool v1 = (n0 + 1 < N);

    for (int k0 = 0; k0 < K; k0 += BK) {
        const int L = (K - k0 < BK) ? (K - k0) : BK;  // chunk len (always %4==0 here)
        // stage W[k0..k0+L) x NOUTP (pad cols >= wcols with 0)
        for (int i = tid; i < L * NOUTP; i += 256) {
            int k = i / NOUTP;
            int c = i - k * NOUTP;
            Wl[i] = (c < wcols) ? W[(size_t)(k0 + k) * wcols + c] : 0.0f;
        }
        __syncthreads();

        const int L4 = L / 4;
        for (int k4 = 0; k4 < L4; ++k4) {
            float4 a0f = v0 ? A4[(size_t)n0 * K4 + k0 / 4 + k4] : make_float4(0, 0, 0, 0);
            float4 a1f = v1 ? A4[(size_t)(n0 + 1) * K4 + k0 / 4 + k4] : make_float4(0, 0, 0, 0);
            float a0[4] = {a0f.x, a0f.y, a0f.z, a0f.w};
            float a1[4] = {a1f.x, a1f.y, a1f.z, a1f.w};
#pragma unroll
            for (int kk = 0; kk < 4; ++kk) {
#pragma unroll
                for (int jj = 0; jj < NJ4; ++jj) {
                    const float4 w = *(const float4*)&Wl[(k4 * 4 + kk) * NOUTP + (jj * TJ + tj) * 4];
                    acc[0][jj * 4 + 0] = fmaf(a0[kk], w.x, acc[0][jj * 4 + 0]);
                    acc[0][jj * 4 + 1] = fmaf(a0[kk], w.y, acc[0][jj * 4 + 1]);
                    acc[0][jj * 4 + 2] = fmaf(a0[kk], w.z, acc[0][jj * 4 + 2]);
                    acc[0][jj * 4 + 3] = fmaf(a0[kk], w.w, acc[0][jj * 4 + 3]);
                    acc[1][jj * 4 + 0] = fmaf(a1[kk], w.x, acc[1][jj * 4 + 0]);
                    acc[1][jj * 4 + 1] = fmaf(a1[kk], w.y, acc[1][jj * 4 + 1]);
                    acc[1][jj * 4 + 2] = fmaf(a1[kk], w.z, acc[1][jj * 4 + 2]);
                    acc[1][jj * 4 + 3] = fmaf(a1[kk], w.w, acc[1][jj * 4 + 3]);
                }
            }
        }
        __syncthreads();
    }

#pragma unroll
    for (int m = 0; m < M2; ++m) {
        const int n = n0 + m;
        if (n < N) {
            const float s_in = EPI ? nin[n] : 1.0f;
            const float s_out = EPI ? nout[n] : 1.0f;
#pragma unroll
            for (int jj = 0; jj < NJ4; ++jj) {
                const int c0 = (jj * TJ + tj) * 4;
                float4 o;
                float v0e = acc[m][jj * 4 + 0] * s_in;
                float v1e = acc[m][jj * 4 + 1] * s_in;
                float v2e = acc[m][jj * 4 + 2] * s_in;
                float v3e = acc[m][jj * 4 + 3] * s_in;
                if (EPI) {
                    v0e = fmaxf(v0e + bias[c0 + 0], 0.0f) * s_out;
                    v1e = fmaxf(v1e + bias[c0 + 1], 0.0f) * s_out;
                    v2e = fmaxf(v2e + bias[c0 + 2], 0.0f) * s_out;
                    v3e = fmaxf(v3e + bias[c0 + 3], 0.0f) * s_out;
                }
                o.x = v0e; o.y = v1e; o.z = v2e; o.w = v3e;
                *(float4*)&out[(size_t)n * NOUTP + c0] = o;
            }
        }
    }
}

// ---------------- final: out[n,f] = relu(aggP[n*48+f] * nin[n] + b3[f]), f<47 ----------------
__global__ __launch_bounds__(256) void final_kernel(const float* __restrict__ aggP,
                                                    float* __restrict__ out,
                                                    const float* __restrict__ nin,
                                                    const float* __restrict__ b3, int N) {
    int i = blockIdx.x * 256 + threadIdx.x;
    int total = N * 47;
    if (i < total) {
        int n = i / 47;
        int f = i - n * 47;
        out[i] = fmaxf(aggP[(size_t)n * 48 + f] * nin[n] + b3[f], 0.0f);
    }
}

extern "C" void kernel_launch(void* const* d_in, const int* in_sizes, int n_in,
                              void* d_out, int out_size, void* d_ws, size_t ws_size,
                              hipStream_t stream) {
    const float* x  = (const float*)d_in[0];
    const int*   ei = (const int*)d_in[1];
    const float* W1 = (const float*)d_in[2];
    const float* b1 = (const float*)d_in[3];
    const float* W2 = (const float*)d_in[4];
    const float* b2 = (const float*)d_in[5];
    const float* W3 = (const float*)d_in[6];
    const float* b3 = (const float*)d_in[7];
    float* out = (float*)d_out;

    const int N = NN;
    const int E = in_sizes[1] / 2;
    const int* src = ei;
    const int* dst = ei + E;

    float* ws = (float*)d_ws;
    float* norm_out = ws;                      // N
    float* norm_in  = ws + N;                  // N
    float* bufA = ws + 2 * (size_t)N;          // N x 128 (agg buffer / y+aggP for layer 3)
    float* bufB = bufA + (size_t)N * 128;      // N x 128 (h buffer)
    float* bufY = bufA;                        // N x 48 (layer-3 pre-propagated, padded)
    float* bufP = bufA + (size_t)N * 48;       // N x 48 (layer-3 aggregation, padded)

    // degrees -> norms
    hipMemsetAsync(norm_out, 0, 2 * (size_t)N * sizeof(float), stream);
    degree_kernel<<<(E + 255) / 256, 256, 0, stream>>>(src, dst, norm_out, norm_in, E);
    norm_kernel<<<(N + 255) / 256, 256, 0, stream>>>(norm_out, norm_in, N);

    // ---- layer 1: agg1 = scatter(x * no, 100); h1' = relu(agg1@W1 *nin + b1) * no ----
    hipMemsetAsync(bufA, 0, (size_t)N * 100 * sizeof(float), stream);
    {
        int total = E * 25;
        scatter4_kernel<25, true><<<(total + 255) / 256, 256, 0, stream>>>(
            (const float4*)x, src, dst, norm_out, bufA, E);
    }
    gemm_kernel<100, 128, 8, true><<<(N + 63) / 64, 256, 0, stream>>>(
        bufA, W1, 128, b1, norm_in, norm_out, bufB, N);

    // ---- layer 2: agg2 = scatter(h1', 128); h2' = relu(agg2@W2 *nin + b2) * no ----
    hipMemsetAsync(bufA, 0, (size_t)N * 128 * sizeof(float), stream);
    {
        int total = E * 32;
        scatter4_kernel<32, false><<<(total + 255) / 256, 256, 0, stream>>>(
            (const float4*)bufB, src, dst, nullptr, bufA, E);
    }
    gemm_kernel<128, 128, 8, true><<<(N + 63) / 64, 256, 0, stream>>>(
        bufA, W2, 128, b2, norm_in, norm_out, bufB, N);

    // ---- layer 3 (reordered): y' = h2' @ W3 (padded 48); aggP = scatter(y', 48);
    //      out = relu(aggP * nin + b3) ----
    gemm_kernel<128, 48, 4, false><<<(N + 127) / 128, 256, 0, stream>>>(
        bufB, W3, 47, nullptr, nullptr, nullptr, bufY, N);
    hipMemsetAsync(bufP, 0, (size_t)N * 48 * sizeof(float), stream);
    {
        int total = E * 12;
        scatter4_kernel<12, false><<<(total + 255) / 256, 256, 0, stream>>>(
            (const float4*)bufY, src, dst, nullptr, bufP, E);
    }
    final_kernel<<<(N * 47 + 255) / 256, 256, 0, stream>>>(bufP, out, norm_in, b3, N);
}

// Round 3
// 1207.289 us; speedup vs baseline: 2.9297x; 2.9297x over previous
//
#include <hip/hip_runtime.h>

#define NN 100000

// ================= degree count (int) =================
__global__ __launch_bounds__(256) void count_kernel(const int* __restrict__ src,
                                                    const int* __restrict__ dst,
                                                    int* degO, int* degI, int E) {
    int e = blockIdx.x * 256 + threadIdx.x;
    if (e < E) {
        atomicAdd(&degO[src[e]], 1);
        atomicAdd(&degI[dst[e]], 1);
    }
}

__global__ __launch_bounds__(256) void norm_kernel(const int* __restrict__ degO,
                                                   const int* __restrict__ degI,
                                                   float* no, float* ni, int N) {
    int i = blockIdx.x * 256 + threadIdx.x;
    if (i < N) {
        no[i] = rsqrtf(fmaxf((float)degO[i], 1.0f));
        ni[i] = rsqrtf(fmaxf((float)degI[i], 1.0f));
    }
}

// ================= exclusive scan of degI -> row_start (3-phase) =================
__global__ __launch_bounds__(256) void scan1_kernel(const int* __restrict__ deg,
                                                    int* exsc, int* partials, int N) {
    __shared__ int sh[256];
    int i = blockIdx.x * 256 + threadIdx.x;
    int v = (i < N) ? deg[i] : 0;
    sh[threadIdx.x] = v;
    __syncthreads();
    for (int off = 1; off < 256; off <<= 1) {
        int t = (threadIdx.x >= off) ? sh[threadIdx.x - off] : 0;
        __syncthreads();
        sh[threadIdx.x] += t;
        __syncthreads();
    }
    if (i < N) exsc[i] = sh[threadIdx.x] - v;
    if (threadIdx.x == 255) partials[blockIdx.x] = sh[255];
}

__global__ __launch_bounds__(512) void scan2_kernel(int* partials, int nb) {
    __shared__ int sh[512];
    int v = (threadIdx.x < nb) ? partials[threadIdx.x] : 0;
    sh[threadIdx.x] = v;
    __syncthreads();
    for (int off = 1; off < 512; off <<= 1) {
        int t = (threadIdx.x >= off) ? sh[threadIdx.x - off] : 0;
        __syncthreads();
        sh[threadIdx.x] += t;
        __syncthreads();
    }
    if (threadIdx.x < nb) partials[threadIdx.x] = sh[threadIdx.x] - v;  // exclusive
}

__global__ __launch_bounds__(256) void scan3_kernel(int* exsc, const int* __restrict__ partials,
                                                    int* cursor, int N) {
    int i = blockIdx.x * 256 + threadIdx.x;
    if (i < N) {
        int r = exsc[i] + partials[blockIdx.x];
        exsc[i] = r;
        cursor[i] = r;
    }
}

// ================= CSR fill: csr_src[slot(dst)] = src =================
__global__ __launch_bounds__(256) void fill_kernel(const int* __restrict__ src,
                                                   const int* __restrict__ dst,
                                                   int* cursor, int* csr_src, int E) {
    int e = blockIdx.x * 256 + threadIdx.x;
    if (e < E) {
        int pos = atomicAdd(&cursor[dst[e]], 1);
        csr_src[pos] = src[e];
    }
}

// ================= gather-aggregate: out[n] = sum_{e in(n)} h[src(e)] (*no[src]) =================
// TPN lanes per node, lane handles one float4 column-group (active if lane < D4).
template <int D4, int TPN, bool SCALE>
__global__ __launch_bounds__(256) void aggregate_kernel(const float4* __restrict__ h,
                                                        const int* __restrict__ row_start,
                                                        const int* __restrict__ deg,
                                                        const int* __restrict__ csr_src,
                                                        const float* __restrict__ no,
                                                        float4* __restrict__ out, int N) {
    int tid = blockIdx.x * 256 + threadIdx.x;
    int node = tid / TPN;
    int lane = tid % TPN;
    if (node >= N) return;
    const bool active = lane < D4;
    float4 acc = make_float4(0.f, 0.f, 0.f, 0.f);
    const int start = row_start[node];
    const int d = deg[node];
    int j = 0;
    for (; j + 1 < d; j += 2) {
        int s0 = csr_src[start + j];
        int s1 = csr_src[start + j + 1];
        if (active) {
            float4 v0 = h[(size_t)s0 * D4 + lane];
            float4 v1 = h[(size_t)s1 * D4 + lane];
            float c0 = SCALE ? no[s0] : 1.0f;
            float c1 = SCALE ? no[s1] : 1.0f;
            acc.x += v0.x * c0 + v1.x * c1;
            acc.y += v0.y * c0 + v1.y * c1;
            acc.z += v0.z * c0 + v1.z * c1;
            acc.w += v0.w * c0 + v1.w * c1;
        }
    }
    if (j < d) {
        int s0 = csr_src[start + j];
        if (active) {
            float4 v0 = h[(size_t)s0 * D4 + lane];
            float c0 = SCALE ? no[s0] : 1.0f;
            acc.x += v0.x * c0;
            acc.y += v0.y * c0;
            acc.z += v0.z * c0;
            acc.w += v0.w * c0;
        }
    }
    if (active) out[(size_t)node * D4 + lane] = acc;
}

// ================= layer-3 fused aggregate: out[n,c<47] = relu(agg*nin + b3) =================
template <int D4, int TPN>
__global__ __launch_bounds__(256) void aggregate_final_kernel(const float4* __restrict__ y,
                                                              const int* __restrict__ row_start,
                                                              const int* __restrict__ deg,
                                                              const int* __restrict__ csr_src,
                                                              const float* __restrict__ nin,
                                                              const float* __restrict__ b3,
                                                              float* __restrict__ out, int N) {
    int tid = blockIdx.x * 256 + threadIdx.x;
    int node = tid / TPN;
    int lane = tid % TPN;
    if (node >= N) return;
    const bool active = lane < D4;
    float4 acc = make_float4(0.f, 0.f, 0.f, 0.f);
    const int start = row_start[node];
    const int d = deg[node];
    int j = 0;
    for (; j + 1 < d; j += 2) {
        int s0 = csr_src[start + j];
        int s1 = csr_src[start + j + 1];
        if (active) {
            float4 v0 = y[(size_t)s0 * D4 + lane];
            float4 v1 = y[(size_t)s1 * D4 + lane];
            acc.x += v0.x + v1.x;
            acc.y += v0.y + v1.y;
            acc.z += v0.z + v1.z;
            acc.w += v0.w + v1.w;
        }
    }
    if (j < d) {
        int s0 = csr_src[start + j];
        if (active) {
            float4 v0 = y[(size_t)s0 * D4 + lane];
            acc.x += v0.x;
            acc.y += v0.y;
            acc.z += v0.z;
            acc.w += v0.w;
        }
    }
    if (active) {
        float s = nin[node];
        float vals[4] = {acc.x, acc.y, acc.z, acc.w};
        int c0 = lane * 4;
#pragma unroll
        for (int k = 0; k < 4; ++k) {
            int c = c0 + k;
            if (c < 47) out[(size_t)node * 47 + c] = fmaxf(vals[k] * s + b3[c], 0.0f);
        }
    }
}

// ================= GEMM: out = [relu(] A@W *nin + b [) * nout] =================
template <int K, int NOUTP, int TJ, bool EPI>
__global__ __launch_bounds__(256, 4) void gemm_kernel(const float* __restrict__ A,
                                                      const float* __restrict__ W, const int wcols,
                                                      const float* __restrict__ bias,
                                                      const float* __restrict__ nin,
                                                      const float* __restrict__ nout,
                                                      float* __restrict__ out, const int N) {
    constexpr int BK = 64;
    constexpr int ROWS = 256 / TJ;
    constexpr int M2 = 2;
    constexpr int BM = ROWS * M2;
    constexpr int NJ4 = NOUTP / (TJ * 4);

    __shared__ __align__(16) float Wl[BK * NOUTP];

    const int tid = threadIdx.x;
    const int tj = tid % TJ;
    const int r = tid / TJ;
    const int n0 = blockIdx.x * BM + r * M2;
    const int K4 = K / 4;

    float acc[M2][NJ4 * 4];
#pragma unroll
    for (int m = 0; m < M2; ++m)
#pragma unroll
        for (int j = 0; j < NJ4 * 4; ++j) acc[m][j] = 0.0f;

    const float4* A4 = (const float4*)A;
    const bool v0 = (n0 < N);
    const bool v1 = (n0 + 1 < N);

    for (int k0 = 0; k0 < K; k0 += BK) {
        const int L = (K - k0 < BK) ? (K - k0) : BK;
        for (int i = tid; i < L * NOUTP; i += 256) {
            int k = i / NOUTP;
            int c = i - k * NOUTP;
            Wl[i] = (c < wcols) ? W[(size_t)(k0 + k) * wcols + c] : 0.0f;
        }
        __syncthreads();

        const int L4 = L / 4;
        for (int k4 = 0; k4 < L4; ++k4) {
            float4 a0f = v0 ? A4[(size_t)n0 * K4 + k0 / 4 + k4] : make_float4(0, 0, 0, 0);
            float4 a1f = v1 ? A4[(size_t)(n0 + 1) * K4 + k0 / 4 + k4] : make_float4(0, 0, 0, 0);
            float a0[4] = {a0f.x, a0f.y, a0f.z, a0f.w};
            float a1[4] = {a1f.x, a1f.y, a1f.z, a1f.w};
#pragma unroll
            for (int kk = 0; kk < 4; ++kk) {
#pragma unroll
                for (int jj = 0; jj < NJ4; ++jj) {
                    const float4 w = *(const float4*)&Wl[(k4 * 4 + kk) * NOUTP + (jj * TJ + tj) * 4];
                    acc[0][jj * 4 + 0] = fmaf(a0[kk], w.x, acc[0][jj * 4 + 0]);
                    acc[0][jj * 4 + 1] = fmaf(a0[kk], w.y, acc[0][jj * 4 + 1]);
                    acc[0][jj * 4 + 2] = fmaf(a0[kk], w.z, acc[0][jj * 4 + 2]);
                    acc[0][jj * 4 + 3] = fmaf(a0[kk], w.w, acc[0][jj * 4 + 3]);
                    acc[1][jj * 4 + 0] = fmaf(a1[kk], w.x, acc[1][jj * 4 + 0]);
                    acc[1][jj * 4 + 1] = fmaf(a1[kk], w.y, acc[1][jj * 4 + 1]);
                    acc[1][jj * 4 + 2] = fmaf(a1[kk], w.z, acc[1][jj * 4 + 2]);
                    acc[1][jj * 4 + 3] = fmaf(a1[kk], w.w, acc[1][jj * 4 + 3]);
                }
            }
        }
        __syncthreads();
    }

#pragma unroll
    for (int m = 0; m < M2; ++m) {
        const int n = n0 + m;
        if (n < N) {
            const float s_in = EPI ? nin[n] : 1.0f;
            const float s_out = EPI ? nout[n] : 1.0f;
#pragma unroll
            for (int jj = 0; jj < NJ4; ++jj) {
                const int c0 = (jj * TJ + tj) * 4;
                float v0e = acc[m][jj * 4 + 0] * s_in;
                float v1e = acc[m][jj * 4 + 1] * s_in;
                float v2e = acc[m][jj * 4 + 2] * s_in;
                float v3e = acc[m][jj * 4 + 3] * s_in;
                if (EPI) {
                    v0e = fmaxf(v0e + bias[c0 + 0], 0.0f) * s_out;
                    v1e = fmaxf(v1e + bias[c0 + 1], 0.0f) * s_out;
                    v2e = fmaxf(v2e + bias[c0 + 2], 0.0f) * s_out;
                    v3e = fmaxf(v3e + bias[c0 + 3], 0.0f) * s_out;
                }
                float4 o = make_float4(v0e, v1e, v2e, v3e);
                *(float4*)&out[(size_t)n * NOUTP + c0] = o;
            }
        }
    }
}

extern "C" void kernel_launch(void* const* d_in, const int* in_sizes, int n_in,
                              void* d_out, int out_size, void* d_ws, size_t ws_size,
                              hipStream_t stream) {
    const float* x  = (const float*)d_in[0];
    const int*   ei = (const int*)d_in[1];
    const float* W1 = (const float*)d_in[2];
    const float* b1 = (const float*)d_in[3];
    const float* W2 = (const float*)d_in[4];
    const float* b2 = (const float*)d_in[5];
    const float* W3 = (const float*)d_in[6];
    const float* b3 = (const float*)d_in[7];
    float* out = (float*)d_out;

    const int N = NN;
    const int E = in_sizes[1] / 2;
    const int* src = ei;
    const int* dst = ei + E;

    // ---- workspace layout ----
    float* ws = (float*)d_ws;
    float* norm_out = ws;                       // N f
    float* norm_in  = ws + N;                   // N f
    float* bufA = ws + 2 * (size_t)N;           // N x 128 f (agg; aliased as bufY N x 48)
    float* bufB = bufA + (size_t)N * 128;       // N x 128 f (h)
    int* ip = (int*)(bufB + (size_t)N * 128);
    int* degO      = ip;                        // N i
    int* degI      = ip + N;                    // N i
    int* row_start = ip + 2 * (size_t)N;        // N i
    int* cursor    = ip + 3 * (size_t)N;        // N i
    int* csr_src   = ip + 4 * (size_t)N;        // E i
    int* partials  = csr_src + E;               // 512 i
    float* bufY = bufA;                         // N x 48

    const int NB = (N + 255) / 256;             // 391 scan blocks

    // ---- degrees, norms, CSR ----
    hipMemsetAsync(degO, 0, 2 * (size_t)N * sizeof(int), stream);
    count_kernel<<<(E + 255) / 256, 256, 0, stream>>>(src, dst, degO, degI, E);
    norm_kernel<<<NB, 256, 0, stream>>>(degO, degI, norm_out, norm_in, N);
    scan1_kernel<<<NB, 256, 0, stream>>>(degI, row_start, partials, N);
    scan2_kernel<<<1, 512, 0, stream>>>(partials, NB);
    scan3_kernel<<<NB, 256, 0, stream>>>(row_start, partials, cursor, N);
    fill_kernel<<<(E + 255) / 256, 256, 0, stream>>>(src, dst, cursor, csr_src, E);

    // ---- layer 1: agg1 = gather-agg(x * no, 100); h1' = relu(agg1@W1 *nin + b1) * no ----
    aggregate_kernel<25, 32, true><<<(N * 32 + 255) / 256, 256, 0, stream>>>(
        (const float4*)x, row_start, degI, csr_src, norm_out, (float4*)bufA, N);
    gemm_kernel<100, 128, 8, true><<<(N + 63) / 64, 256, 0, stream>>>(
        bufA, W1, 128, b1, norm_in, norm_out, bufB, N);

    // ---- layer 2: agg2 = gather-agg(h1', 128); h2' = relu(agg2@W2 *nin + b2) * no ----
    aggregate_kernel<32, 32, false><<<(N * 32 + 255) / 256, 256, 0, stream>>>(
        (const float4*)bufB, row_start, degI, csr_src, nullptr, (float4*)bufA, N);
    gemm_kernel<128, 128, 8, true><<<(N + 63) / 64, 256, 0, stream>>>(
        bufA, W2, 128, b2, norm_in, norm_out, bufB, N);

    // ---- layer 3 (reordered): y' = h2'@W3 (pad 48); out = relu(gather-agg(y')*nin + b3) ----
    gemm_kernel<128, 48, 4, false><<<(N + 127) / 128, 256, 0, stream>>>(
        bufB, W3, 47, nullptr, nullptr, nullptr, bufY, N);
    aggregate_final_kernel<12, 16><<<(N * 16 + 255) / 256, 256, 0, stream>>>(
        (const float4*)bufY, row_start, degI, csr_src, norm_in, b3, out, N);
}